// Round 9
// baseline (354.965 us; speedup 1.0000x reference)
//
#include <hip/hip_runtime.h>
#include <math.h>

// UNISURF renderer, MI355X — two-kernel MFMA edition.
// R8 -> R9: (a) march+secant and render split into separate kernels (slimmer
// register footprints -> natural occupancy, no launch-bounds spill trap);
// (b) eval restructured to M-quarters (acc[8] = 32 VGPRs per call);
// (c) secant refinement reuses the staged fp16 W2 via uniform-d MFMA quarter
// evals instead of 2048 strided global W2 loads per hit ray.
//
// Verified fragment layout (R5-R8 passed):
//   A: row = lane&15,  k = 4*(lane>>4) + (e&3) + 16*(e>>2)   (e = 0..7)
//   B: col = lane&15,  same k-map
//   C: col = lane&15,  row = 4*(lane>>4) + reg

#define HID 128
#define NEARF 0.8f
#define FARF  1.8f

typedef __attribute__((ext_vector_type(8))) _Float16 half8;
typedef __attribute__((ext_vector_type(4))) float f32x4;

__device__ __forceinline__ float sigmoidf_(float x) { return 1.0f / (1.0f + expf(-x)); }

// One M-quarter (16 sample-rows) of the 128->128->heads MLP on MFMA.
// dq = depth used for this lane's A-row (sample row = lane&15 of quarter mq).
// Scatters per-sample results into sred[mq*16 + row] (+64/128/192 if RGB).
template<bool RGB>
__device__ __forceinline__ void eval_q(
    const float* __restrict__ su, const float* __restrict__ sv,
    const _Float16* __restrict__ sW2F,
    const float* __restrict__ sB2, const float* __restrict__ sWo,
    const float* __restrict__ sWc, float* __restrict__ sred,
    int mq, float dq, int lane)
{
    const int g = lane >> 4, nl = lane & 15;
    f32x4 acc[8];
#pragma unroll
    for (int nt = 0; nt < 8; ++nt) acc[nt] = (f32x4){0.f, 0.f, 0.f, 0.f};

#pragma unroll
    for (int kt = 0; kt < 4; ++kt) {
        const float* uk = su + kt * 32 + 4 * g;
        const float* vk = sv + kt * 32 + 4 * g;
        const float4 u0 = *reinterpret_cast<const float4*>(uk);
        const float4 u1 = *reinterpret_cast<const float4*>(uk + 16);
        const float4 v0 = *reinterpret_cast<const float4*>(vk);
        const float4 v1 = *reinterpret_cast<const float4*>(vk + 16);
        const float ue[8] = {u0.x, u0.y, u0.z, u0.w, u1.x, u1.y, u1.z, u1.w};
        const float ve[8] = {v0.x, v0.y, v0.z, v0.w, v1.x, v1.y, v1.z, v1.w};
        half8 Ah, Al;
#pragma unroll
        for (int e = 0; e < 8; ++e) {
            const float h = fmaxf(fmaf(dq, ve[e], ue[e]), 0.f);
            const _Float16 hh = (_Float16)h;
            Ah[e] = hh;
            Al[e] = (_Float16)(h - (float)hh);
        }
#pragma unroll
        for (int nt = 0; nt < 8; ++nt) {
            const int frag = (kt * 8 + nt) * 64 + lane;
            const half8 B = *reinterpret_cast<const half8*>(&sW2F[frag * 8]);
            acc[nt] = __builtin_amdgcn_mfma_f32_16x16x32_f16(Ah, B, acc[nt], 0, 0, 0);
            acc[nt] = __builtin_amdgcn_mfma_f32_16x16x32_f16(Al, B, acc[nt], 0, 0, 0);
        }
    }

    // epilogue: h2 = relu(acc + b2); head partials
    float pl[4], p0[4], p1[4], p2[4];
#pragma unroll
    for (int r = 0; r < 4; ++r) { pl[r] = 0.f; if (RGB) { p0[r] = 0.f; p1[r] = 0.f; p2[r] = 0.f; } }
#pragma unroll
    for (int nt = 0; nt < 8; ++nt) {
        const int j = nt * 16 + nl;
        const float b2l = sB2[j], wol = sWo[j];
        float wc0 = 0.f, wc1 = 0.f, wc2 = 0.f;
        if (RGB) { wc0 = sWc[j * 3 + 0]; wc1 = sWc[j * 3 + 1]; wc2 = sWc[j * 3 + 2]; }
#pragma unroll
        for (int r = 0; r < 4; ++r) {
            const float h2 = fmaxf(acc[nt][r] + b2l, 0.f);
            pl[r] = fmaf(h2, wol, pl[r]);
            if (RGB) {
                p0[r] = fmaf(h2, wc0, p0[r]);
                p1[r] = fmaf(h2, wc1, p1[r]);
                p2[r] = fmaf(h2, wc2, p2[r]);
            }
        }
    }
    // reduce across the 16 lanes of each g-group (j varies across them)
#pragma unroll
    for (int off = 1; off < 16; off <<= 1) {
#pragma unroll
        for (int r = 0; r < 4; ++r) {
            pl[r] += __shfl_xor(pl[r], off);
            if (RGB) {
                p0[r] += __shfl_xor(p0[r], off);
                p1[r] += __shfl_xor(p1[r], off);
                p2[r] += __shfl_xor(p2[r], off);
            }
        }
    }
    if (nl == 0) {
#pragma unroll
        for (int r = 0; r < 4; ++r) {
            const int m = mq * 16 + 4 * g + r;
            sred[m] = pl[r];
            if (RGB) { sred[64 + m] = p0[r]; sred[128 + m] = p1[r]; sred[192 + m] = p2[r]; }
        }
    }
}

__device__ __forceinline__ void stage_w2(const float* __restrict__ W2,
                                         _Float16* __restrict__ sW2F, int tid) {
    for (int s = tid; s < 2048; s += 256) {
        const int ln = s & 63, ntg = (s >> 6) & 7, kt = s >> 9;
        const int n = ntg * 16 + (ln & 15), gg = ln >> 4;
        half8 hp;
#pragma unroll
        for (int e = 0; e < 8; ++e) {
            const int k = kt * 32 + 4 * gg + (e & 3) + ((e >> 2) << 4);
            hp[e] = (_Float16)W2[k * HID + n];
        }
        *reinterpret_cast<half8*>(&sW2F[s * 8]) = hp;
    }
}

// ---------------- kernel 1: march + secant -> d_i, objmask ------------------
extern "C" __global__ void __launch_bounds__(256, 2)
k_march(const float* __restrict__ raysDir, const float* __restrict__ raysOrg,
        const float* __restrict__ W1, const float* __restrict__ b1,
        const float* __restrict__ W2, const float* __restrict__ b2,
        const float* __restrict__ Wo, const float* __restrict__ bo,
        float* __restrict__ wsD, float* __restrict__ wsM, int nRays)
{
    __shared__ __align__(16) _Float16 sW2F[2048 * 8];   // 32KB
    __shared__ __align__(16) float sU[4][HID];
    __shared__ __align__(16) float sV[4][HID];
    __shared__ __align__(16) float sB2[HID];
    __shared__ __align__(16) float sWoS[HID];
    __shared__ __align__(16) float sRedM[4][64];

    const int tid = threadIdx.x;
    stage_w2(W2, sW2F, tid);
    if (tid < HID) { sB2[tid] = b2[tid]; sWoS[tid] = Wo[tid]; }
    __syncthreads();

    const int w = tid >> 6, lane = tid & 63, nl = lane & 15;
    const int ray = blockIdx.x * 4 + w;
    if (ray >= nRays) return;

    const float ox = raysOrg[ray * 3 + 0], oy = raysOrg[ray * 3 + 1], oz = raysOrg[ray * 3 + 2];
    const float dx = raysDir[ray * 3 + 0], dy = raysDir[ray * 3 + 1], dz = raysDir[ray * 3 + 2];
    const float nrm = sqrtf(dx * dx + dy * dy + dz * dz);
    const float rdx = dx / nrm, rdy = dy / nrm, rdz = dz / nrm;
    const float bo0 = bo[0];
    const float ST = 1.0f / 127.0f;

    float* su = sU[w];
    float* sv = sV[w];
    float* sred = sRedM[w];
    for (int k = lane; k < HID; k += 64) {
        const float w1x = W1[k], w1y = W1[HID + k], w1z = W1[2 * HID + k];
        su[k] = ox * w1x + oy * w1y + oz * w1z + b1[k];
        sv[k] = rdx * w1x + rdy * w1y + rdz * w1z;
    }

    // ---- chunk A (samples 0..63) ----
#pragma unroll 1
    for (int mq = 0; mq < 4; ++mq)
        eval_q<false>(su, sv, sW2F, sB2, sWoS, nullptr, sred,
                      mq, NEARF + (float)(mq * 16 + nl) * ST, lane);
    asm volatile("s_waitcnt lgkmcnt(0)" ::: "memory");
    const float fA = sigmoidf_(sred[lane] + bo0) - 0.5f;

    const float f0 = __shfl(fA, 0);
    const float fAn = __shfl_down(fA, 1);
    const bool crossA = (lane < 63) && (fA * fAn < 0.f);
    const unsigned long long balA = __ballot(crossA);

    int idx = 0; float f_lo = 0.f, f_hi = 0.f; bool haschange = false;
    if (balA) {
        const int l = __ffsll(balA) - 1;
        idx = l; f_lo = __shfl(fA, l); f_hi = __shfl(fA, l + 1); haschange = true;
    } else if (f0 < 0.f) {
        // ---- chunk B (samples 64..127) ----
        const float b0 = NEARF + 64.0f * ST;
#pragma unroll 1
        for (int mq = 0; mq < 4; ++mq)
            eval_q<false>(su, sv, sW2F, sB2, sWoS, nullptr, sred,
                          mq, b0 + (float)(mq * 16 + nl) * ST, lane);
        asm volatile("s_waitcnt lgkmcnt(0)" ::: "memory");
        const float fB = sigmoidf_(sred[lane] + bo0) - 0.5f;
        float fprev = __shfl_up(fB, 1);
        const float fA63 = __shfl(fA, 63);
        if (lane == 0) fprev = fA63;
        const bool crossB = (fprev * fB < 0.f);   // pair s = 63 + lane
        const unsigned long long balB = __ballot(crossB);
        if (balB) {
            const int l = __ffsll(balB) - 1;
            idx = 63 + l; f_lo = __shfl(fprev, l); f_hi = __shfl(fB, l); haschange = true;
        }
    }

    // ---- secant (uniform-d MFMA quarter evals, fp16 W2 path) ----
    float d_i; float obj = 0.f;
    if (f0 >= 0.f) {
        d_i = 0.f;
    } else if (haschange && (f_lo < 0.f)) {
        float dlo = NEARF + (float)idx * ST;
        float dhi = NEARF + (float)(idx + 1) * ST;
        float flo = f_lo, fhi = f_hi;
#pragma unroll 1
        for (int itn = 0; itn < 8; ++itn) {
            float den = fhi - flo;
            if (fabsf(den) < 1e-12f) den = 1e-12f;
            const float dmid = dlo - flo * (dhi - dlo) / den;
            eval_q<false>(su, sv, sW2F, sB2, sWoS, nullptr, sred, 0, dmid, lane);
            asm volatile("s_waitcnt lgkmcnt(0)" ::: "memory");
            const float fmid = sigmoidf_(sred[nl] + bo0) - 0.5f;
            if (fmid < 0.f) { dlo = dmid; flo = fmid; }
            else            { dhi = dmid; fhi = fmid; }
        }
        float den = fhi - flo;
        if (fabsf(den) < 1e-12f) den = 1e-12f;
        d_i = dlo - flo * (dhi - dlo) / den;
        obj = 1.f;
    } else {
        d_i = __builtin_inff();
    }
    if (lane == 0) { wsD[ray] = d_i; wsM[ray] = obj; }
}

// ---------------- kernel 2: render ------------------------------------------
extern "C" __global__ void __launch_bounds__(256, 2)
k_render(const float* __restrict__ raysDir, const float* __restrict__ raysOrg,
         const float* __restrict__ W1, const float* __restrict__ b1,
         const float* __restrict__ W2, const float* __restrict__ b2,
         const float* __restrict__ Wo, const float* __restrict__ bo,
         const float* __restrict__ Wc, const float* __restrict__ bc,
         const int* __restrict__ itp,
         const float* __restrict__ wsD, const float* __restrict__ wsM,
         float* __restrict__ outRGB, float* __restrict__ outD, float* __restrict__ outM,
         int nRays)
{
    __shared__ __align__(16) _Float16 sW2F[2048 * 8];   // 32KB
    __shared__ __align__(16) float sU[4][HID];
    __shared__ __align__(16) float sV[4][HID];
    __shared__ __align__(16) float sB2[HID];
    __shared__ __align__(16) float sWoS[HID];
    __shared__ __align__(16) float sWc[HID * 3];
    __shared__ __align__(16) float sRedR[4][256];

    const int tid = threadIdx.x;
    stage_w2(W2, sW2F, tid);
    if (tid < HID) { sB2[tid] = b2[tid]; sWoS[tid] = Wo[tid]; }
    for (int i = tid; i < HID * 3; i += 256) sWc[i] = Wc[i];
    __syncthreads();

    const int w = tid >> 6, lane = tid & 63, nl = lane & 15;
    const int ray = blockIdx.x * 4 + w;
    if (ray >= nRays) return;

    const float ox = raysOrg[ray * 3 + 0], oy = raysOrg[ray * 3 + 1], oz = raysOrg[ray * 3 + 2];
    const float dx = raysDir[ray * 3 + 0], dy = raysDir[ray * 3 + 1], dz = raysDir[ray * 3 + 2];
    const float nrm = sqrtf(dx * dx + dy * dy + dz * dz);
    const float rdx = dx / nrm, rdy = dy / nrm, rdz = dz / nrm;
    const float bo0 = bo[0];

    float* su = sU[w];
    float* sv = sV[w];
    float* sred = sRedR[w];
    for (int k = lane; k < HID; k += 64) {
        const float w1x = W1[k], w1y = W1[HID + k], w1z = W1[2 * HID + k];
        su[k] = ox * w1x + oy * w1y + oz * w1z + b1[k];
        sv[k] = rdx * w1x + rdy * w1y + rdz * w1z;
    }

    const float d_i = wsD[ray];
    const bool objmask = wsM[ray] > 0.5f;

    const int it = itp[0];
    const float delta = fmaxf(0.1f * expf(-2e-5f * (float)it), 0.01f);
    const float dsafe = objmask ? d_i : 1.0f;
    const float dnp = fmaxf(dsafe - delta, NEARF);
    const float dfp = fminf(dsafe + delta, FARF);
    const float t = (float)lane * (1.0f / 63.0f);
    const float depth = objmask ? (dnp * (1.f - t) + dfp * t)
                                : (NEARF * (1.f - t) + FARF * t);

#pragma unroll 1
    for (int mq = 0; mq < 4; ++mq) {
        const float dR = __shfl(depth, mq * 16 + nl);
        eval_q<true>(su, sv, sW2F, sB2, sWoS, sWc, sred, mq, dR, lane);
    }
    asm volatile("s_waitcnt lgkmcnt(0)" ::: "memory");
    const float lg = sred[lane];
    const float alpha = sigmoidf_(lg + bo0);
    float rc[3];
#pragma unroll
    for (int c = 0; c < 3; ++c) {
        const float x = sred[64 + 64 * c + lane]
            + rdx * Wc[128 * 3 + c] + rdy * Wc[129 * 3 + c] + rdz * Wc[130 * 3 + c]
            + bc[c];
        rc[c] = sigmoidf_(x);
    }

    // transmittance: exclusive prefix product of (1 - alpha + 1e-6)
    const float om = 1.f - alpha + 1e-6f;
    float incl = om;
#pragma unroll
    for (int off = 1; off < 64; off <<= 1) {
        const float p = __shfl_up(incl, off);
        if (lane >= off) incl *= p;
    }
    float trans = __shfl_up(incl, 1);
    if (lane == 0) trans = 1.f;
    const float wgt = alpha * trans;

    float s0 = wgt * rc[0], s1 = wgt * rc[1], s2 = wgt * rc[2], sd = wgt * depth;
#pragma unroll
    for (int off = 32; off; off >>= 1) {
        s0 += __shfl_xor(s0, off);
        s1 += __shfl_xor(s1, off);
        s2 += __shfl_xor(s2, off);
        sd += __shfl_xor(sd, off);
    }
    if (lane == 0) {
        outRGB[ray * 3 + 0] = s0;
        outRGB[ray * 3 + 1] = s1;
        outRGB[ray * 3 + 2] = s2;
        outD[ray] = sd;
        outM[ray] = objmask ? 1.f : 0.f;
    }
}

extern "C" void kernel_launch(void* const* d_in, const int* in_sizes, int n_in,
                              void* d_out, int out_size, void* d_ws, size_t ws_size,
                              hipStream_t stream) {
    (void)n_in; (void)out_size; (void)ws_size;
    const int R = in_sizes[0] / 3;
    float* out = reinterpret_cast<float*>(d_out);
    float* wsD = reinterpret_cast<float*>(d_ws);
    float* wsM = wsD + R;
    dim3 grid((R + 3) / 4), block(256);
    hipLaunchKernelGGL(k_march, grid, block, 0, stream,
        (const float*)d_in[0], (const float*)d_in[1], (const float*)d_in[2],
        (const float*)d_in[3], (const float*)d_in[4], (const float*)d_in[5],
        (const float*)d_in[6], (const float*)d_in[7],
        wsD, wsM, R);
    hipLaunchKernelGGL(k_render, grid, block, 0, stream,
        (const float*)d_in[0], (const float*)d_in[1], (const float*)d_in[2],
        (const float*)d_in[3], (const float*)d_in[4], (const float*)d_in[5],
        (const float*)d_in[6], (const float*)d_in[7], (const float*)d_in[8],
        (const float*)d_in[9], (const int*)d_in[10],
        wsD, wsM,
        out, out + 3 * (size_t)R, out + 4 * (size_t)R, R);
}

// Round 10
// 261.175 us; speedup vs baseline: 1.3591x; 1.3591x over previous
//
#include <hip/hip_runtime.h>
#include <math.h>

// UNISURF renderer, MI355X — single-kernel slim-MFMA edition.
// R9 -> R10: back to ONE kernel at __launch_bounds__(256,1). Empirical law
// from R3/R7/R8/R9: launch_bounds(256,N) caps VGPR at ~256/N on this
// toolchain; any N>=2 puts the cap below natural use (~150) and triggers a
// catastrophic scratch spill (0.5-1 GB/dispatch). (256,1) is the only safe
// setting; occupancy must come from structurally low register pressure:
// eval_q (acc[8]=32 VGPRs) + MFMA secant (no global W2 GEMV). Natural VGPR
// target <=170 -> 3 waves/SIMD; LDS 42.6KB -> 3 blocks/CU.
//
// Verified fragment layout (R5-R9 passed):
//   A: row = lane&15,  k = 4*(lane>>4) + (e&3) + 16*(e>>2)   (e = 0..7)
//   B: col = lane&15,  same k-map
//   C: col = lane&15,  row = 4*(lane>>4) + reg

#define HID 128
#define NEARF 0.8f
#define FARF  1.8f

typedef __attribute__((ext_vector_type(8))) _Float16 half8;
typedef __attribute__((ext_vector_type(4))) float f32x4;

__device__ __forceinline__ float sigmoidf_(float x) { return 1.0f / (1.0f + expf(-x)); }

// One M-quarter (16 sample-rows) of the 128->128->heads MLP on MFMA.
// dq = depth for this lane's A-row (sample row = lane&15 of quarter mq).
// Scatters per-sample results into sred[mq*16 + row] (+64/128/192 if RGB).
template<bool RGB>
__device__ __forceinline__ void eval_q(
    const float* __restrict__ su, const float* __restrict__ sv,
    const _Float16* __restrict__ sW2F,
    const float* __restrict__ sB2, const float* __restrict__ sWo,
    const float* __restrict__ sWc, float* __restrict__ sred,
    int mq, float dq, int lane)
{
    const int g = lane >> 4, nl = lane & 15;
    f32x4 acc[8];
#pragma unroll
    for (int nt = 0; nt < 8; ++nt) acc[nt] = (f32x4){0.f, 0.f, 0.f, 0.f};

#pragma unroll
    for (int kt = 0; kt < 4; ++kt) {
        const float* uk = su + kt * 32 + 4 * g;
        const float* vk = sv + kt * 32 + 4 * g;
        const float4 u0 = *reinterpret_cast<const float4*>(uk);
        const float4 u1 = *reinterpret_cast<const float4*>(uk + 16);
        const float4 v0 = *reinterpret_cast<const float4*>(vk);
        const float4 v1 = *reinterpret_cast<const float4*>(vk + 16);
        const float ue[8] = {u0.x, u0.y, u0.z, u0.w, u1.x, u1.y, u1.z, u1.w};
        const float ve[8] = {v0.x, v0.y, v0.z, v0.w, v1.x, v1.y, v1.z, v1.w};
        half8 Ah, Al;
#pragma unroll
        for (int e = 0; e < 8; ++e) {
            const float h = fmaxf(fmaf(dq, ve[e], ue[e]), 0.f);
            const _Float16 hh = (_Float16)h;
            Ah[e] = hh;
            Al[e] = (_Float16)(h - (float)hh);
        }
#pragma unroll
        for (int nt = 0; nt < 8; ++nt) {
            const int frag = (kt * 8 + nt) * 64 + lane;
            const half8 B = *reinterpret_cast<const half8*>(&sW2F[frag * 8]);
            acc[nt] = __builtin_amdgcn_mfma_f32_16x16x32_f16(Ah, B, acc[nt], 0, 0, 0);
            acc[nt] = __builtin_amdgcn_mfma_f32_16x16x32_f16(Al, B, acc[nt], 0, 0, 0);
        }
    }

    // epilogue: h2 = relu(acc + b2); head partials
    float pl[4], p0[4], p1[4], p2[4];
#pragma unroll
    for (int r = 0; r < 4; ++r) { pl[r] = 0.f; if (RGB) { p0[r] = 0.f; p1[r] = 0.f; p2[r] = 0.f; } }
#pragma unroll
    for (int nt = 0; nt < 8; ++nt) {
        const int j = nt * 16 + nl;
        const float b2l = sB2[j], wol = sWo[j];
        float wc0 = 0.f, wc1 = 0.f, wc2 = 0.f;
        if (RGB) { wc0 = sWc[j * 3 + 0]; wc1 = sWc[j * 3 + 1]; wc2 = sWc[j * 3 + 2]; }
#pragma unroll
        for (int r = 0; r < 4; ++r) {
            const float h2 = fmaxf(acc[nt][r] + b2l, 0.f);
            pl[r] = fmaf(h2, wol, pl[r]);
            if (RGB) {
                p0[r] = fmaf(h2, wc0, p0[r]);
                p1[r] = fmaf(h2, wc1, p1[r]);
                p2[r] = fmaf(h2, wc2, p2[r]);
            }
        }
    }
    // reduce across the 16 lanes of each g-group (j varies across them)
#pragma unroll
    for (int off = 1; off < 16; off <<= 1) {
#pragma unroll
        for (int r = 0; r < 4; ++r) {
            pl[r] += __shfl_xor(pl[r], off);
            if (RGB) {
                p0[r] += __shfl_xor(p0[r], off);
                p1[r] += __shfl_xor(p1[r], off);
                p2[r] += __shfl_xor(p2[r], off);
            }
        }
    }
    if (nl == 0) {
#pragma unroll
        for (int r = 0; r < 4; ++r) {
            const int m = mq * 16 + 4 * g + r;
            sred[m] = pl[r];
            if (RGB) { sred[64 + m] = p0[r]; sred[128 + m] = p1[r]; sred[192 + m] = p2[r]; }
        }
    }
}

extern "C" __global__ void __launch_bounds__(256, 1)
unisurf_mfma_kernel(
    const float* __restrict__ raysDir, const float* __restrict__ raysOrg,
    const float* __restrict__ W1, const float* __restrict__ b1,
    const float* __restrict__ W2, const float* __restrict__ b2,
    const float* __restrict__ Wo, const float* __restrict__ bo,
    const float* __restrict__ Wc, const float* __restrict__ bc,
    const int* __restrict__ itp,
    float* __restrict__ outRGB, float* __restrict__ outD, float* __restrict__ outM,
    int nRays)
{
    __shared__ __align__(16) _Float16 sW2F[2048 * 8];   // B-frag fp16 (32KB)
    __shared__ __align__(16) float sU[4][HID];
    __shared__ __align__(16) float sV[4][HID];
    __shared__ __align__(16) float sB2[HID];
    __shared__ __align__(16) float sWoS[HID];
    __shared__ __align__(16) float sWc[HID * 3];
    __shared__ __align__(16) float sRed[4][256];

    const int tid = threadIdx.x;
    // ---- stage W2 into MFMA B-fragment order, fp16 -------------------------
    for (int s = tid; s < 2048; s += 256) {
        const int ln = s & 63, ntg = (s >> 6) & 7, kt = s >> 9;
        const int n = ntg * 16 + (ln & 15), gg = ln >> 4;
        half8 hp;
#pragma unroll
        for (int e = 0; e < 8; ++e) {
            const int k = kt * 32 + 4 * gg + (e & 3) + ((e >> 2) << 4);
            hp[e] = (_Float16)W2[k * HID + n];
        }
        *reinterpret_cast<half8*>(&sW2F[s * 8]) = hp;
    }
    if (tid < HID) { sB2[tid] = b2[tid]; sWoS[tid] = Wo[tid]; }
    for (int i = tid; i < HID * 3; i += 256) sWc[i] = Wc[i];
    __syncthreads();

    const int w = tid >> 6, lane = tid & 63, nl = lane & 15;
    const int ray = blockIdx.x * 4 + w;
    if (ray >= nRays) return;

    // ---- per-ray setup -----------------------------------------------------
    const float ox = raysOrg[ray * 3 + 0], oy = raysOrg[ray * 3 + 1], oz = raysOrg[ray * 3 + 2];
    const float dx = raysDir[ray * 3 + 0], dy = raysDir[ray * 3 + 1], dz = raysDir[ray * 3 + 2];
    const float nrm = sqrtf(dx * dx + dy * dy + dz * dz);
    const float rdx = dx / nrm, rdy = dy / nrm, rdz = dz / nrm;
    const float bo0 = bo[0];
    const float ST = 1.0f / 127.0f;

    float* su = sU[w];
    float* sv = sV[w];
    float* sred = sRed[w];
    for (int k = lane; k < HID; k += 64) {
        const float w1x = W1[k], w1y = W1[HID + k], w1z = W1[2 * HID + k];
        su[k] = ox * w1x + oy * w1y + oz * w1z + b1[k];
        sv[k] = rdx * w1x + rdy * w1y + rdz * w1z;
    }

    // ---- marching: chunk A (samples 0..63) ---------------------------------
#pragma unroll 1
    for (int mq = 0; mq < 4; ++mq)
        eval_q<false>(su, sv, sW2F, sB2, sWoS, nullptr, sred,
                      mq, NEARF + (float)(mq * 16 + nl) * ST, lane);
    asm volatile("s_waitcnt lgkmcnt(0)" ::: "memory");
    const float fA = sigmoidf_(sred[lane] + bo0) - 0.5f;

    const float f0 = __shfl(fA, 0);
    const float fAn = __shfl_down(fA, 1);
    const bool crossA = (lane < 63) && (fA * fAn < 0.f);
    const unsigned long long balA = __ballot(crossA);

    int idx = 0; float f_lo = 0.f, f_hi = 0.f; bool haschange = false;
    if (balA) {
        const int l = __ffsll(balA) - 1;
        idx = l; f_lo = __shfl(fA, l); f_hi = __shfl(fA, l + 1); haschange = true;
    } else if (f0 < 0.f) {
        // ---- chunk B (samples 64..127) -------------------------------------
        const float b0 = NEARF + 64.0f * ST;
#pragma unroll 1
        for (int mq = 0; mq < 4; ++mq)
            eval_q<false>(su, sv, sW2F, sB2, sWoS, nullptr, sred,
                          mq, b0 + (float)(mq * 16 + nl) * ST, lane);
        asm volatile("s_waitcnt lgkmcnt(0)" ::: "memory");
        const float fB = sigmoidf_(sred[lane] + bo0) - 0.5f;
        float fprev = __shfl_up(fB, 1);
        const float fA63 = __shfl(fA, 63);
        if (lane == 0) fprev = fA63;
        const bool crossB = (fprev * fB < 0.f);   // pair s = 63 + lane
        const unsigned long long balB = __ballot(crossB);
        if (balB) {
            const int l = __ffsll(balB) - 1;
            idx = 63 + l; f_lo = __shfl(fprev, l); f_hi = __shfl(fB, l); haschange = true;
        }
    }

    // ---- secant (uniform-d MFMA quarter evals, fp16 W2 path) ---------------
    float d_i;
    bool objmask = false;
    if (f0 >= 0.f) {
        d_i = 0.f;
    } else if (haschange && (f_lo < 0.f)) {
        float dlo = NEARF + (float)idx * ST;
        float dhi = NEARF + (float)(idx + 1) * ST;
        float flo = f_lo, fhi = f_hi;
#pragma unroll 1
        for (int itn = 0; itn < 8; ++itn) {
            float den = fhi - flo;
            if (fabsf(den) < 1e-12f) den = 1e-12f;
            const float dmid = dlo - flo * (dhi - dlo) / den;
            eval_q<false>(su, sv, sW2F, sB2, sWoS, nullptr, sred, 0, dmid, lane);
            asm volatile("s_waitcnt lgkmcnt(0)" ::: "memory");
            const float fmid = sigmoidf_(sred[nl] + bo0) - 0.5f;
            if (fmid < 0.f) { dlo = dmid; flo = fmid; }
            else            { dhi = dmid; fhi = fmid; }
        }
        float den = fhi - flo;
        if (fabsf(den) < 1e-12f) den = 1e-12f;
        d_i = dlo - flo * (dhi - dlo) / den;
        objmask = true;
    } else {
        d_i = __builtin_inff();
    }

    // ---- render: 64 samples, lane = sample ---------------------------------
    const int it = itp[0];
    const float delta = fmaxf(0.1f * expf(-2e-5f * (float)it), 0.01f);
    const float dsafe = objmask ? d_i : 1.0f;
    const float dnp = fmaxf(dsafe - delta, NEARF);
    const float dfp = fminf(dsafe + delta, FARF);
    const float t = (float)lane * (1.0f / 63.0f);
    const float depth = objmask ? (dnp * (1.f - t) + dfp * t)
                                : (NEARF * (1.f - t) + FARF * t);

#pragma unroll 1
    for (int mq = 0; mq < 4; ++mq) {
        const float dR = __shfl(depth, mq * 16 + nl);
        eval_q<true>(su, sv, sW2F, sB2, sWoS, sWc, sred, mq, dR, lane);
    }
    asm volatile("s_waitcnt lgkmcnt(0)" ::: "memory");
    const float lg = sred[lane];
    const float alpha = sigmoidf_(lg + bo0);
    float rc[3];
#pragma unroll
    for (int c = 0; c < 3; ++c) {
        const float x = sred[64 + 64 * c + lane]
            + rdx * Wc[128 * 3 + c] + rdy * Wc[129 * 3 + c] + rdz * Wc[130 * 3 + c]
            + bc[c];
        rc[c] = sigmoidf_(x);
    }

    // transmittance: exclusive prefix product of (1 - alpha + 1e-6)
    const float om = 1.f - alpha + 1e-6f;
    float incl = om;
#pragma unroll
    for (int off = 1; off < 64; off <<= 1) {
        const float p = __shfl_up(incl, off);
        if (lane >= off) incl *= p;
    }
    float trans = __shfl_up(incl, 1);
    if (lane == 0) trans = 1.f;
    const float wgt = alpha * trans;

    float s0 = wgt * rc[0], s1 = wgt * rc[1], s2 = wgt * rc[2], sd = wgt * depth;
#pragma unroll
    for (int off = 32; off; off >>= 1) {
        s0 += __shfl_xor(s0, off);
        s1 += __shfl_xor(s1, off);
        s2 += __shfl_xor(s2, off);
        sd += __shfl_xor(sd, off);
    }
    if (lane == 0) {
        outRGB[ray * 3 + 0] = s0;
        outRGB[ray * 3 + 1] = s1;
        outRGB[ray * 3 + 2] = s2;
        outD[ray] = sd;
        outM[ray] = objmask ? 1.f : 0.f;
    }
}

extern "C" void kernel_launch(void* const* d_in, const int* in_sizes, int n_in,
                              void* d_out, int out_size, void* d_ws, size_t ws_size,
                              hipStream_t stream) {
    (void)n_in; (void)out_size; (void)d_ws; (void)ws_size;
    const int R = in_sizes[0] / 3;
    float* out = reinterpret_cast<float*>(d_out);
    dim3 grid((R + 3) / 4), block(256);
    hipLaunchKernelGGL(unisurf_mfma_kernel, grid, block, 0, stream,
        (const float*)d_in[0], (const float*)d_in[1], (const float*)d_in[2],
        (const float*)d_in[3], (const float*)d_in[4], (const float*)d_in[5],
        (const float*)d_in[6], (const float*)d_in[7], (const float*)d_in[8],
        (const float*)d_in[9], (const int*)d_in[10],
        out, out + 3 * (size_t)R, out + 4 * (size_t)R, R);
}